// Round 1
// baseline (561.503 us; speedup 1.0000x reference)
//
#include <hip/hip_runtime.h>
#include <math.h>

#define TEMP 0.07f
#define EPSN 1e-12f

__device__ __forceinline__ float wave_reduce_sum(float v) {
    #pragma unroll
    for (int off = 32; off > 0; off >>= 1)
        v += __shfl_xor(v, off, 64);
    return v;
}

__device__ __forceinline__ float wave_reduce_max(float v) {
    #pragma unroll
    for (int off = 32; off > 0; off >>= 1)
        v = fmaxf(v, __shfl_xor(v, off, 64));
    return v;
}

// ---------------------------------------------------------------------------
// Kernel 1: persistent mean-pool with 2-stage register double-buffering.
// 768 blocks x 256 threads = 3072 waves, all co-resident (3 blocks/CU).
//   slow waves: gw in [0,2048)  -> 32 units each, unit = 4 rows of 392 floats
//               (65536 units = 2 tensors x 32768)
//   fast waves: gw in [2048,3072) -> 32 units each, unit = 1 row of 1568 floats
//               (32768 units = 2 tensors x 16384)
// Each iteration issues the NEXT unit's loads before reducing the CURRENT
// unit, so ~8-16 x 1KB loads stay in flight per wave through the shuffle
// phase (compiler emits counted vmcnt). Converts the old 10us-lifetime /
// 6KB-delivered throwaway waves into steady streaming.
// ---------------------------------------------------------------------------
__global__ __launch_bounds__(256) void pool_kernel(
    const float* __restrict__ fpv_slow, const float* __restrict__ fpv_fast,
    const float* __restrict__ tpv_slow, const float* __restrict__ tpv_fast,
    float* __restrict__ pool /* [2][64][2304] */)
{
    const int wv   = (int)(threadIdx.x >> 6);
    const int lane = (int)(threadIdx.x & 63);
    const int gw   = (int)blockIdx.x * 4 + wv;
    const float4 z4 = make_float4(0.f, 0.f, 0.f, 0.f);

    if (gw < 2048) {                          // ---- slow tensors ----
        const float4* pf = (const float4*)fpv_slow;
        const float4* pt = (const float4*)tpv_slow;
        const bool lo = lane < 34;
        float4 xa0,xa1,xa2,xa3,xb0,xb1,xb2,xb3;
        float4 ya0,ya1,ya2,ya3,yb0,yb1,yb2,yb3;

#define SLOAD(U,A0,A1,A2,A3,B0,B1,B2,B3)  do {                                \
        const int u_ = (U);                                                   \
        const float4* q_ = ((u_ < 32768) ? pf : pt)                           \
                           + (size_t)(u_ & 32767) * 392 + lane;               \
        A0 = q_[0]; A1 = q_[98]; A2 = q_[196]; A3 = q_[294];                  \
        B0 = z4; B1 = z4; B2 = z4; B3 = z4;                                   \
        if (lo) { B0 = q_[64]; B1 = q_[162]; B2 = q_[260]; B3 = q_[358]; }    \
    } while (0)

#define SRED(U,A0,A1,A2,A3,B0,B1,B2,B3)  do {                                 \
        const int u_ = (U);                                                   \
        float s0 = (A0.x+A0.y+A0.z+A0.w) + (B0.x+B0.y+B0.z+B0.w);             \
        float s1 = (A1.x+A1.y+A1.z+A1.w) + (B1.x+B1.y+B1.z+B1.w);             \
        float s2 = (A2.x+A2.y+A2.z+A2.w) + (B2.x+B2.y+B2.z+B2.w);             \
        float s3 = (A3.x+A3.y+A3.z+A3.w) + (B3.x+B3.y+B3.z+B3.w);             \
        s0 = wave_reduce_sum(s0); s1 = wave_reduce_sum(s1);                   \
        s2 = wave_reduce_sum(s2); s3 = wave_reduce_sum(s3);                   \
        if (lane == 0) {                                                      \
            const int tn_ = u_ >> 15, rb_ = (u_ & 32767) * 4;                 \
            const int b_ = rb_ >> 11, c_ = rb_ & 2047;                        \
            float4 o;                                                         \
            o.x = s0*(1.0f/392.0f); o.y = s1*(1.0f/392.0f);                   \
            o.z = s2*(1.0f/392.0f); o.w = s3*(1.0f/392.0f);                   \
            *(float4*)&pool[tn_ * (64*2304) + b_ * 2304 + c_] = o;            \
        }                                                                     \
    } while (0)

        SLOAD(gw, xa0,xa1,xa2,xa3,xb0,xb1,xb2,xb3);
        #pragma unroll 1
        for (int it = 0; it < 30; it += 2) {
            SLOAD(gw + (it+1)*2048, ya0,ya1,ya2,ya3,yb0,yb1,yb2,yb3);
            SRED (gw + it*2048,     xa0,xa1,xa2,xa3,xb0,xb1,xb2,xb3);
            SLOAD(gw + (it+2)*2048, xa0,xa1,xa2,xa3,xb0,xb1,xb2,xb3);
            SRED (gw + (it+1)*2048, ya0,ya1,ya2,ya3,yb0,yb1,yb2,yb3);
        }
        SLOAD(gw + 31*2048, ya0,ya1,ya2,ya3,yb0,yb1,yb2,yb3);
        SRED (gw + 30*2048, xa0,xa1,xa2,xa3,xb0,xb1,xb2,xb3);
        SRED (gw + 31*2048, ya0,ya1,ya2,ya3,yb0,yb1,yb2,yb3);
#undef SLOAD
#undef SRED
    } else {                                  // ---- fast tensors ----
        const int fw = gw - 2048;             // 0..1023
        const float4* pf = (const float4*)fpv_fast;
        const float4* pt = (const float4*)tpv_fast;
        const bool t8 = lane < 8;
        float4 xa0,xa1,xa2,xa3,xa4,xa5,xt;
        float4 ya0,ya1,ya2,ya3,ya4,ya5,yt;

#define FLOAD(U,A0,A1,A2,A3,A4,A5,T)  do {                                    \
        const int u_ = (U);                                                   \
        const float4* q_ = ((u_ < 16384) ? pf : pt)                           \
                           + (size_t)(u_ & 16383) * 392 + lane;               \
        A0 = q_[0];   A1 = q_[64];  A2 = q_[128];                             \
        A3 = q_[192]; A4 = q_[256]; A5 = q_[320];                             \
        T = z4; if (t8) T = q_[384];                                          \
    } while (0)

#define FRED(U,A0,A1,A2,A3,A4,A5,T)  do {                                     \
        const int u_ = (U);                                                   \
        float s = (A0.x+A0.y+A0.z+A0.w) + (A1.x+A1.y+A1.z+A1.w)               \
                + (A2.x+A2.y+A2.z+A2.w) + (A3.x+A3.y+A3.z+A3.w)               \
                + (A4.x+A4.y+A4.z+A4.w) + (A5.x+A5.y+A5.z+A5.w)               \
                + (T.x+T.y+T.z+T.w);                                          \
        s = wave_reduce_sum(s);                                               \
        if (lane == 0) {                                                      \
            const int tn_ = u_ >> 14, row_ = u_ & 16383;                      \
            pool[tn_ * (64*2304) + (row_ >> 8) * 2304 + 2048 + (row_ & 255)]  \
                = s * (1.0f/1568.0f);                                         \
        }                                                                     \
    } while (0)

        FLOAD(fw, xa0,xa1,xa2,xa3,xa4,xa5,xt);
        #pragma unroll 1
        for (int it = 0; it < 30; it += 2) {
            FLOAD(fw + (it+1)*1024, ya0,ya1,ya2,ya3,ya4,ya5,yt);
            FRED (fw + it*1024,     xa0,xa1,xa2,xa3,xa4,xa5,xt);
            FLOAD(fw + (it+2)*1024, xa0,xa1,xa2,xa3,xa4,xa5,xt);
            FRED (fw + (it+1)*1024, ya0,ya1,ya2,ya3,ya4,ya5,yt);
        }
        FLOAD(fw + 31*1024, ya0,ya1,ya2,ya3,ya4,ya5,yt);
        FRED (fw + 30*1024, xa0,xa1,xa2,xa3,xa4,xa5,xt);
        FRED (fw + 31*1024, ya0,ya1,ya2,ya3,ya4,ya5,yt);
#undef FLOAD
#undef FRED
    }
}

// ---------------------------------------------------------------------------
// Kernel 2: split-K GEMV partials on RAW pooled x (l2norm folded out:
// l2norm(x)@W = scale1 * (x@W)). Grid 1152 = (h*64+b)*9 + ks; each block
// handles a K-chunk of 256. Wave wv covers 64 k's; lane -> cols 4l..4l+3.
// gp[idx][c] = sum_{k in chunk} x[k]*W[k][c].   (unchanged — verified)
// ---------------------------------------------------------------------------
__global__ __launch_bounds__(256) void gemv_kernel(
    const float* __restrict__ pool,
    const float* __restrict__ W_f, const float* __restrict__ W_t,
    float* __restrict__ gp /* [1152][256] */)
{
    __shared__ float xs[256];
    __shared__ float partial[4][256];

    const int tid = threadIdx.x, wv = tid >> 6, lane = tid & 63;
    const int idx = blockIdx.x;
    const int ks  = idx % 9;
    const int hb  = idx / 9;
    const int h   = hb >> 6, b = hb & 63;
    const float* W = h ? W_t : W_f;

    xs[tid] = pool[h * (64 * 2304) + b * 2304 + ks * 256 + tid];
    __syncthreads();

    float4 acc = make_float4(0.f, 0.f, 0.f, 0.f);
    const float4* Wv = (const float4*)W + (size_t)(ks * 256 + wv * 64) * 64 + lane;
    #pragma unroll 8
    for (int kk = 0; kk < 64; ++kk) {
        const float xk = xs[wv * 64 + kk];
        const float4 w4 = Wv[(size_t)kk * 64];
        acc.x += xk * w4.x; acc.y += xk * w4.y;
        acc.z += xk * w4.z; acc.w += xk * w4.w;
    }
    *(float4*)&partial[wv][4 * lane] = acc;
    __syncthreads();

    gp[(size_t)idx * 256 + tid] =
        partial[0][tid] + partial[1][tid] + partial[2][tid] + partial[3][tid];
}

// ---------------------------------------------------------------------------
// Kernel 3: finalize head (unchanged — verified).
// ---------------------------------------------------------------------------
__global__ __launch_bounds__(256) void finalize_kernel(
    const float* __restrict__ pool, const float* __restrict__ gp,
    const float* __restrict__ b_f, const float* __restrict__ b_t,
    float* __restrict__ ft /* [2][64][256] */)
{
    __shared__ float red[8];
    const int tid = threadIdx.x, wv = tid >> 6, lane = tid & 63;
    const int h = blockIdx.x >> 6, b = blockIdx.x & 63;

    const float* xrow = pool + h * (64 * 2304) + b * 2304;
    float ss = 0.0f;
    #pragma unroll
    for (int r = 0; r < 9; ++r) {
        const float v = xrow[tid + r * 256];
        ss += v * v;
    }
    ss = wave_reduce_sum(ss);
    if (lane == 0) red[wv] = ss;
    __syncthreads();
    const float scale1 = 1.0f / fmaxf(sqrtf(red[0] + red[1] + red[2] + red[3]), EPSN);

    float y = 0.0f;
    const float* g = gp + (size_t)(h * 64 + b) * 9 * 256;
    #pragma unroll
    for (int ks = 0; ks < 9; ++ks) y += g[ks * 256 + tid];
    const float* bias = h ? b_t : b_f;
    y = y * scale1 + bias[tid];

    const float ss2 = wave_reduce_sum(y * y);
    if (lane == 0) red[4 + wv] = ss2;
    __syncthreads();
    const float scale2 = 1.0f / fmaxf(sqrtf(red[4] + red[5] + red[6] + red[7]), EPSN);

    ft[h * (64 * 256) + b * 256 + tid] = y * scale2;
}

// ---------------------------------------------------------------------------
// Kernel 4: loss (unchanged — verified).
// ---------------------------------------------------------------------------
__global__ __launch_bounds__(256) void loss_kernel(
    const float* __restrict__ ft,
    const float* __restrict__ lv, const float* __restrict__ lvlt,
    const float* __restrict__ ln, const float* __restrict__ lnlt,
    const int* __restrict__ same_idx,
    float* __restrict__ out)
{
    __shared__ float fs[256];
    __shared__ float sim[64];
    __shared__ float pos_sh;

    const int i   = blockIdx.x;
    const int tid = threadIdx.x, wv = tid >> 6, lane = tid & 63;
    const float* f = ft;
    const float* t = ft + 64 * 256;

    fs[tid] = f[i * 256 + tid];
    if (wv == 3) {
        float s = 0.0f;
        for (int k = lane; k < 97; k += 64)  s += lv[i * 97 + k]  * lvlt[i * 97 + k];
        for (int k = lane; k < 300; k += 64) s += ln[i * 300 + k] * lnlt[i * 300 + k];
        s = wave_reduce_sum(s);
        if (lane == 0) pos_sh = 0.5f * s;
    }
    __syncthreads();

    const float4 a = ((const float4*)fs)[lane];
    for (int jj = 0; jj < 16; ++jj) {
        const int j = wv * 16 + jj;
        const float4 b4 = ((const float4*)(t + j * 256))[lane];
        float d = a.x * b4.x + a.y * b4.y + a.z * b4.z + a.w * b4.w;
        d = wave_reduce_sum(d);
        if (lane == 0) sim[j] = d / TEMP;
    }
    __syncthreads();

    if (wv == 0) {
        const int si = same_idx[i];
        const float pos = pos_sh;
        const float x = sim[lane];
        const float m = wave_reduce_max(x);
        const float e = expf(x - m);
        const float s = wave_reduce_sum(e);
        const float lse = logf(s);
        float w;
        if (si == 2)      w = (lane == i) ? 1.0f : 0.0f;
        else if (si == 0) w = 1.0f / 64.0f;
        else {
            const float neg = (1.0f - pos) * (1.0f / 63.0f);
            w = (lane == i) ? pos : neg;
        }
        const float dotv = wave_reduce_sum(w * x);
        if (lane == 0) atomicAdd(out, (m + lse - dotv) * (1.0f / 64.0f));
    }
}

extern "C" void kernel_launch(void* const* d_in, const int* in_sizes, int n_in,
                              void* d_out, int out_size, void* d_ws, size_t ws_size,
                              hipStream_t stream) {
    const float* fpv_slow   = (const float*)d_in[0];
    const float* fpv_fast   = (const float*)d_in[1];
    const float* tpv_slow   = (const float*)d_in[2];
    const float* tpv_fast   = (const float*)d_in[3];
    const float* labels_v    = (const float*)d_in[4];
    const float* labels_n    = (const float*)d_in[5];
    const float* labels_v_lt = (const float*)d_in[6];
    const float* labels_n_lt = (const float*)d_in[7];
    const int*   same_idx    = (const int*)d_in[8];
    const float* W_fpv = (const float*)d_in[9];
    const float* b_fpv = (const float*)d_in[10];
    const float* W_tpv = (const float*)d_in[11];
    const float* b_tpv = (const float*)d_in[12];

    float* pool = (float*)d_ws;                  // 2*64*2304 = 294912 floats
    float* gp   = pool + 2 * 64 * 2304;          // 1152*256  = 294912 floats
    float* ft   = gp + 1152 * 256;               // 2*64*256  = 32768 floats
    float* out  = (float*)d_out;

    hipMemsetAsync(d_out, 0, sizeof(float) * out_size, stream);

    pool_kernel<<<768, 256, 0, stream>>>(fpv_slow, fpv_fast, tpv_slow, tpv_fast, pool);
    gemv_kernel<<<1152, 256, 0, stream>>>(pool, W_fpv, W_tpv, gp);
    finalize_kernel<<<128, 256, 0, stream>>>(pool, gp, b_fpv, b_tpv, ft);
    loss_kernel<<<64, 256, 0, stream>>>(ft, labels_v, labels_v_lt, labels_n, labels_n_lt,
                                        same_idx, out);
}